// Round 1
// baseline (90.326 us; speedup 1.0000x reference)
//
#include <hip/hip_runtime.h>
#include <cmath>

#define IH 128
#define IW 128
#define NL 256     // strokes per batch image
#define BSZ 512    // brush resolution

// Bilinear tap exactly like reference: load clipped, zero if out of range.
__device__ __forceinline__ float bil_tap(const float* __restrict__ br, int ix, int iy) {
    int cx = min(max(ix, 0), BSZ - 1);
    int cy = min(max(iy, 0), BSZ - 1);
    float v = br[cy * BSZ + cx];
    bool ok = ((unsigned)ix < (unsigned)BSZ) && ((unsigned)iy < (unsigned)BSZ);
    return ok ? v : 0.0f;
}

__global__ __launch_bounds__(256) void render_strokes(
    const float* __restrict__ params,   // (4, 256, 8)
    const float* __restrict__ brushes,  // (2, 1, 512, 512)
    float* __restrict__ out)            // (4, 3, 128, 128)
{
    __shared__ float sw00[NL], sw01[NL], sw02[NL], sw10[NL], sw11[NL], sw12[NL];
    __shared__ float scr[NL], scg[NL], scb[NL];
    __shared__ int   sboff[NL];

    const int b  = blockIdx.z;
    const int tx = threadIdx.x, ty = threadIdx.y;
    const int t  = ty * 16 + tx;

    // ---- Stage 1: per-stroke warp matrices, exact reference op ordering ----
    {
        const float* p = params + ((size_t)b * NL + t) * 8;
        float x0 = p[0], y0 = p[1], w = p[2], h = p[3], th = p[4];
        // jnp.pi (weak f64) * f32 theta -> f32 multiply with f32(pi)
        float ang   = __fmul_rn(3.14159265358979323846f, th);
        // correctly-rounded f32 sin/cos (best match for any <=1ulp host libm)
        float sin_t = (float)sin((double)ang);
        float cos_t = (float)cos((double)ang);
        float a_x = __fsub_rn(1.0f, __fmul_rn(2.0f, x0));
        float a_y = __fsub_rn(1.0f, __fmul_rn(2.0f, y0));
        // H==W==128: the (sin*H)/(W*w) forms scale by exact powers of two ->
        // bit-identical to plain division.
        sw00[t] = __fdiv_rn(cos_t, w);
        sw01[t] = __fdiv_rn(sin_t, w);
        sw02[t] = __fadd_rn(__fdiv_rn(__fmul_rn(a_x, cos_t), w),
                            __fdiv_rn(__fmul_rn(a_y, sin_t), w));
        sw10[t] = __fdiv_rn(-sin_t, h);
        sw11[t] = __fdiv_rn(cos_t, h);
        sw12[t] = __fsub_rn(__fdiv_rn(__fmul_rn(a_y, cos_t), h),
                            __fdiv_rn(__fmul_rn(a_x, sin_t), h));
        scr[t] = p[5]; scg[t] = p[6]; scb[t] = p[7];
        sboff[t] = (h > w) ? 0 : BSZ * BSZ;   // idx = where(h>w, 0, 1)
    }
    __syncthreads();

    // ---- Stage 2: one thread per pixel, reverse scan for last covering stroke ----
    const int px = blockIdx.x * 16 + tx;
    const int py = blockIdx.y * 16 + ty;

    float xs[3], ys[3];
    bool xin[3], yin[3];
#pragma unroll
    for (int d = 0; d < 3; ++d) {
        int qx = px + d - 1, qy = py + d - 1;
        // (2k+1)/128 - 1 is exact in f32 regardless of op fusion
        xs[d] = (2.0f * (float)qx + 1.0f) / 128.0f - 1.0f;
        ys[d] = (2.0f * (float)qy + 1.0f) / 128.0f - 1.0f;
        xin[d] = (qx >= 0) && (qx < IW);
        yin[d] = (qy >= 0) && (qy < IH);
    }

    float o0 = 0.0f, o1 = 0.0f, o2 = 0.0f;
    bool done = false;

    for (int l = NL - 1; l >= 0 && !done; --l) {
        const float w00 = sw00[l], w01 = sw01[l], w02 = sw02[l];
        const float w10 = sw10[l], w11 = sw11[l], w12 = sw12[l];
        const float* __restrict__ br = brushes + sboff[l];

        float axp[3], byp[3], cxp[3], dyp[3];
#pragma unroll
        for (int d = 0; d < 3; ++d) {
            axp[d] = __fmul_rn(xs[d], w00);
            byp[d] = __fmul_rn(ys[d], w01);
            cxp[d] = __fmul_rn(xs[d], w10);
            dyp[d] = __fmul_rn(ys[d], w11);
        }

        // Phase A: geometric validity of all 9 nearest taps (no memory).
        int  tox[9], toy[9];
        bool tact[9];
        bool geo = true;
#pragma unroll
        for (int e = 0; e < 3; ++e) {
#pragma unroll
            for (int d = 0; d < 3; ++d) {
                const int k = e * 3 + d;
                float gx = __fadd_rn(__fadd_rn(axp[d], byp[e]), w02);
                float gy = __fadd_rn(__fadd_rn(cxp[d], dyp[e]), w12);
                float xq = __fmul_rn(__fsub_rn(__fmul_rn(__fadd_rn(gx, 1.0f), 512.0f), 1.0f), 0.5f);
                float yq = __fmul_rn(__fsub_rn(__fmul_rn(__fadd_rn(gy, 1.0f), 512.0f), 1.0f), 0.5f);
                int ix = (int)rintf(xq);   // round-half-to-even, matches jnp.round
                int iy = (int)rintf(yq);
                bool act = xin[d] && yin[e];   // outside image = erosion pad (ignored)
                bool inr = ((unsigned)ix < (unsigned)BSZ) && ((unsigned)iy < (unsigned)BSZ);
                geo = geo && (inr || !act);
                tox[k] = ix; toy[k] = iy; tact[k] = act;
            }
        }
        if (!geo) continue;

        // Phase B: brush>0 test on the (rarely reached) candidate taps.
        bool cov = true;
#pragma unroll
        for (int k = 0; k < 9; ++k) {
            if (tact[k]) cov = cov && (br[toy[k] * BSZ + tox[k]] > 0.0f);
        }
        if (!cov) continue;

        // Covered (alpha==1): composite == replace with this stroke's color.
        float gx = __fadd_rn(__fadd_rn(axp[1], byp[1]), w02);
        float gy = __fadd_rn(__fadd_rn(cxp[1], dyp[1]), w12);
        float xq = __fmul_rn(__fsub_rn(__fmul_rn(__fadd_rn(gx, 1.0f), 512.0f), 1.0f), 0.5f);
        float yq = __fmul_rn(__fsub_rn(__fmul_rn(__fadd_rn(gy, 1.0f), 512.0f), 1.0f), 0.5f);
        float xf = floorf(xq), yf = floorf(yq);
        int   x0i = (int)xf, y0i = (int)yf;
        float wx1 = __fsub_rn(xq, xf), wy1 = __fsub_rn(yq, yf);
        float wx0 = __fsub_rn(1.0f, wx1), wy0 = __fsub_rn(1.0f, wy1);
        float v00 = bil_tap(br, x0i,     y0i);
        float v10 = bil_tap(br, x0i + 1, y0i);
        float v01 = bil_tap(br, x0i,     y0i + 1);
        float v11 = bil_tap(br, x0i + 1, y0i + 1);
        // reference add order: ((t00 + t10) + t01) + t11
        float sv = __fadd_rn(__fadd_rn(__fadd_rn(
                       __fmul_rn(v00, __fmul_rn(wx0, wy0)),
                       __fmul_rn(v10, __fmul_rn(wx1, wy0))),
                       __fmul_rn(v01, __fmul_rn(wx0, wy1))),
                       __fmul_rn(v11, __fmul_rn(wx1, wy1)));
        o0 = __fmul_rn(sv, scr[l]);
        o1 = __fmul_rn(sv, scg[l]);
        o2 = __fmul_rn(sv, scb[l]);
        done = true;
    }

    const size_t pix = (size_t)py * IW + px;
    const size_t img = (size_t)b * 3 * IH * IW;
    out[img + 0 * (IH * IW) + pix] = o0;
    out[img + 1 * (IH * IW) + pix] = o1;
    out[img + 2 * (IH * IW) + pix] = o2;
}

extern "C" void kernel_launch(void* const* d_in, const int* in_sizes, int n_in,
                              void* d_out, int out_size, void* d_ws, size_t ws_size,
                              hipStream_t stream) {
    const float* params  = (const float*)d_in[0];   // (4,256,8) f32
    const float* brushes = (const float*)d_in[1];   // (2,1,512,512) f32
    float* out = (float*)d_out;                     // (4,3,128,128) f32
    dim3 grid(IW / 16, IH / 16, 4);
    dim3 block(16, 16);
    render_strokes<<<grid, block, 0, stream>>>(params, brushes, out);
}